// Round 20
// baseline (198.498 us; speedup 1.0000x reference)
//
#include <hip/hip_runtime.h>

#define THREADS 512
#define DIN 60
#define HN 256
#define DOUT 360

typedef __attribute__((ext_vector_type(8))) short short8;
typedef __attribute__((ext_vector_type(16))) float f32x16;
typedef __attribute__((ext_vector_type(4))) float f32x4;
typedef __attribute__((ext_vector_type(4))) unsigned int u32x4;

// d_ws layout (bytes); total 229376 B
#define WS_CBF   0            // 2048 * 16 B = 32768  (ns-scaled centres + fold, [row][p], p=c^(row&7))
#define WS_W2    32768        // [kc 0..31][row 0..383] short8 = 196608 B (r10-verified layout)

__device__ __forceinline__ short bf16_bits(float f) {   // prep-side only
    union { float f; unsigned u; } v; v.f = f;
    unsigned r = (v.u + 0x7FFFu + ((v.u >> 16) & 1u)) >> 16;
    return (short)(unsigned short)r;
}

__device__ __forceinline__ unsigned pk_bf16(float a, float b) {
    unsigned r;
    asm("v_cvt_pk_bf16_f32 %0, %1, %2" : "=v"(r) : "v"(a), "v"(b));
    return r;   // low16 = bf16(a), high16 = bf16(b)
}

__device__ __forceinline__ void gload16(const void* g, void* lds) {
    __builtin_amdgcn_global_load_lds(
        (const __attribute__((address_space(1))) unsigned int*)(uintptr_t)g,
        (__attribute__((address_space(3))) unsigned int*)(unsigned int)(uintptr_t)lds,
        16, 0, 0);
}

// ---------------- prep: convert/permute constants into ws ----------------
__global__ void prep(const float* __restrict__ centres, const float* __restrict__ sigmas,
                     const float* __restrict__ W2, short* __restrict__ ws)
{
    int t = blockIdx.x * 256 + threadIdx.x;
    if (t < 12288) {
        // W2 frags (r10-verified): [kc][row] short8; k = kc*8..kc*8+7
        int kc = t / 384, row = t % 384;
        short8 v = {0,0,0,0,0,0,0,0};
        if (row < DOUT) {
            int rr = row / 12, jj = row % 12;
            int fcl = rr / 3, kk = rr % 3;
            int o = fcl * 36 + jj * 3 + kk;            // fold output col permutation
            const float* src = W2 + o * HN + kc * 8;
            #pragma unroll
            for (int i = 0; i < 8; ++i) v[i] = bf16_bits(src[i]);
        }
        *(short8*)(ws + (WS_W2 / 2) + t * 8) = v;
    } else if (t < 14336) {
        // cbf (r16-verified ns-fold): [row][p 0..7], p = c ^ (row&7)
        // k<60: nsq*c_k ; k=60,61: hi/lo of -0.5*nsq*c2 (B=1,1) ; k=62,63: -0.5*nsq (B=x2hi,x2lo)
        int j = t - 12288;
        int row = j >> 3, p = j & 7;
        int c = p ^ (row & 7);
        const float* cr = centres + row * DIN;
        float sg = sigmas[row];
        union { unsigned u; float f; } nq;
        nq.u = ((unsigned)(unsigned short)bf16_bits(2.f * sg * sg * 1.44269504088896340736f)) << 16;
        const float nsq = nq.f;                        // bf16-exact
        short8 v = {0,0,0,0,0,0,0,0};
        if (c < 7) {
            #pragma unroll
            for (int i = 0; i < 8; ++i) {
                int k = c * 8 + i;
                if (k < DIN) v[i] = bf16_bits(nsq * cr[k]);
            }
        } else {   // k = 56..63
            #pragma unroll
            for (int i = 0; i < 4; ++i) v[i] = bf16_bits(nsq * cr[56 + i]);
            float c2 = 0.f;
            #pragma unroll
            for (int d = 0; d < DIN; ++d) c2 = fmaf(cr[d], cr[d], c2);
            float T = -0.5f * nsq * c2;
            union { unsigned u; float f; } th;
            th.u = ((unsigned)(unsigned short)bf16_bits(T)) << 16;   // T_hi (bf16-exact)
            v[4] = bf16_bits(th.f);
            v[5] = bf16_bits(T - th.f);
            v[6] = bf16_bits(-0.5f * nsq);
            v[7] = v[6];
        }
        *(short8*)(ws + (WS_CBF / 2) + j * 8) = v;
    }
}

// ---- one 32-row x tile -> fold-packed bf16 B-fragments (r12-verified layout) ----
__device__ __forceinline__ void load_xtile(const float* __restrict__ x, int row0,
                                           int l31, int hi, short8 xb[4]) {
    const float* xr = x + (size_t)(row0 + l31) * DIN;
    f32x4 xa[4][2];
    #pragma unroll
    for (int kt = 0; kt < 4; ++kt) {
        int k0 = kt * 16 + hi * 8;
        xa[kt][0] = *(const f32x4*)(xr + k0);
        xa[kt][1] = (k0 + 4 < DIN) ? *(const f32x4*)(xr + k0 + 4) : (f32x4){0.f,0.f,0.f,0.f};
    }
    float p2 = 0.f;
    #pragma unroll
    for (int kt = 0; kt < 4; ++kt)
        #pragma unroll
        for (int h = 0; h < 2; ++h)
            #pragma unroll
            for (int i = 0; i < 4; ++i) p2 = fmaf(xa[kt][h][i], xa[kt][h][i], p2);
    float x2v = p2 + __shfl_xor(p2, 32);
    union { unsigned u; float f; } hb; hb.u = pk_bf16(x2v, 0.f) << 16;  // x2hi (bf16-exact)
    float x2lo = x2v - hb.f;
    #pragma unroll
    for (int kt = 0; kt < 4; ++kt) {
        union { u32x4 u; short8 s; } a;
        a.u[0] = pk_bf16(xa[kt][0][0], xa[kt][0][1]);
        a.u[1] = pk_bf16(xa[kt][0][2], xa[kt][0][3]);
        a.u[2] = pk_bf16(xa[kt][1][0], xa[kt][1][1]);
        a.u[3] = pk_bf16(xa[kt][1][2], xa[kt][1][3]);
        if (kt == 3) {   // hi lanes: k=60..63 -> B = {1, 1, x2hi, x2lo}
            a.u[2] = hi ? 0x3F803F80u : a.u[2];
            a.u[3] = hi ? pk_bf16(hb.f, x2lo) : a.u[3];
        }
        xb[kt] = a.s;
    }
}

// --- main: r16 fused structure; W2 streamed from L2 into a chunk-deep register
//     double-buffer (LDS pipe freed: only cbf remains in LDS) ---
__global__ __attribute__((amdgpu_flat_work_group_size(THREADS, THREADS),
                          amdgpu_waves_per_eu(2, 2)))
void rbf_main(const float* __restrict__ x, const short* __restrict__ ws,
              float* __restrict__ out)
{
    __shared__ short8 cbf[2048];     // 32 KB: ns-scaled centres + fold (only LDS use)

    const int tid  = threadIdx.x;
    const int w    = tid >> 6;
    const int lane = tid & 63;
    const int l31  = lane & 31;
    const int hi   = lane >> 5;
    const int bid  = blockIdx.x;
    // XCD pair-swizzle (r12): bid and bid^8 share rows, differ in col-half
    const int f     = (bid >> 3) & 1;
    const int sbase = (bid & 7) | ((bid >> 4) << 3);   // 0..127, bijective

    // ---- stage cbf once (async DMA) ----
    #pragma unroll
    for (int i = 0; i < 4; ++i)
        gload16(ws + (WS_CBF / 2) + (i * THREADS + tid) * 8, (char*)cbf + (i * THREADS + tid) * 16);

    // ---- per-lane W2 fragment base: frag(ktg,hi,nt) at wfb[ktg*768 + nt*32] ----
    const short8* const wfb = (const short8*)(ws + (WS_W2 / 2))
                              + (size_t)(hi * 384 + f * 192 + l31);

    // ---- iter-0 x before the barrier ----
    short8 xb[4];
    load_xtile(x, sbase * 1024 + w * 32, l31, hi, xb);

    __syncthreads();   // cbf resident; no barriers, no LDS writes after this

    // ---- prologue: prefetch chunk 0 (ktg 0,1) into buf[0] ----
    short8 buf[2][12];
    const short8* pA = wfb;          // even ktg
    const short8* pB = wfb + 768;    // odd ktg
    #pragma unroll
    for (int j = 0; j < 6; ++j) { buf[0][j] = pA[j * 32]; buf[0][6 + j] = pB[j * 32]; }

    for (int it = 0; it < 4; ++it) {
        const int rb = sbase * 1024 + it * 256 + w * 32;

        f32x16 acc2[6];
        #pragma unroll
        for (int nt = 0; nt < 6; ++nt) acc2[nt] = (f32x16){};

        // ---- fused h-sweep: 8 chunks of 32 h; W2 frags via register dbuf from L2 ----
        #pragma unroll
        for (int nt1 = 0; nt1 < 8; ++nt1) {
            const int cur = nt1 & 1;

            // prefetch next chunk (wrap to chunk 0 for the next iteration at nt1==7)
            if (nt1 < 7) { pA += 1536; pB += 1536; }
            else         { pA = wfb;   pB = wfb + 768; }
            #pragma unroll
            for (int j = 0; j < 6; ++j) {
                buf[cur ^ 1][j]     = pA[j * 32];
                buf[cur ^ 1][6 + j] = pB[j * 32];
            }

            // GEMM1 chunk (cbf from LDS): complete exponent via ns-fold
            f32x16 a1 = (f32x16){};
            const int row = nt1 * 32 + l31;
            __builtin_amdgcn_s_setprio(1);
            #pragma unroll
            for (int kt = 0; kt < 4; ++kt) {
                short8 cf = cbf[row * 8 + ((kt * 2 + hi) ^ (row & 7))];
                a1 = __builtin_amdgcn_mfma_f32_32x32x16_bf16(cf, xb[kt], a1, 0, 0, 0);
            }
            __builtin_amdgcn_s_setprio(0);

            // phi = exp2(min(S,0)) -> packed bf16 words
            unsigned pwl[4][2];
            #pragma unroll
            for (int q = 0; q < 4; ++q) {
                float ph[4];
                #pragma unroll
                for (int j = 0; j < 4; ++j)
                    ph[j] = exp2f(fminf(a1[4 * q + j], 0.f));
                pwl[q][0] = pk_bf16(ph[0], ph[1]);
                pwl[q][1] = pk_bf16(ph[2], ph[3]);
            }

            // 2 GEMM2 k-steps consume pwl + buf[cur] (r12-verified permlane dir)
            #pragma unroll
            for (int m = 0; m < 2; ++m) {
                unsigned d0 = pwl[2 * m][0], s0 = pwl[2 * m + 1][0];
                unsigned d1 = pwl[2 * m][1], s1 = pwl[2 * m + 1][1];
                asm("v_permlane32_swap_b32 %0, %1" : "+v"(d0), "+v"(s0));
                asm("v_permlane32_swap_b32 %0, %1" : "+v"(d1), "+v"(s1));
                union { u32x4 u; short8 s; } bfr;
                bfr.u[0] = d0; bfr.u[1] = d1; bfr.u[2] = s0; bfr.u[3] = s1;

                __builtin_amdgcn_s_setprio(1);
                #pragma unroll
                for (int nt = 0; nt < 6; ++nt)
                    acc2[nt] = __builtin_amdgcn_mfma_f32_32x32x16_bf16(
                        buf[cur][m * 6 + nt], bfr.s, acc2[nt], 0, 0, 0);
                __builtin_amdgcn_s_setprio(0);
            }
        }

        // ---- stores (r12-verified pattern): row rb+l31, 4 cols per reg-quad ----
        {
            float* op = out + (size_t)(rb + l31) * DOUT;
            #pragma unroll
            for (int nt = 0; nt < 6; ++nt) {
                #pragma unroll
                for (int q = 0; q < 4; ++q) {
                    int col = f * 192 + nt * 32 + q * 8 + hi * 4;
                    if (col < DOUT) {
                        f32x4 v;
                        v[0] = acc2[nt][4 * q + 0]; v[1] = acc2[nt][4 * q + 1];
                        v[2] = acc2[nt][4 * q + 2]; v[3] = acc2[nt][4 * q + 3];
                        *(f32x4*)(op + col) = v;
                    }
                }
            }
        }

        // ---- next iter's x AFTER stores (acc2 dead -> register-pressure safe) ----
        if (it < 3)
            load_xtile(x, rb + 256, l31, hi, xb);
    }
}

extern "C" void kernel_launch(void* const* d_in, const int* in_sizes, int n_in,
                              void* d_out, int out_size, void* d_ws, size_t ws_size,
                              hipStream_t stream) {
    const float* x       = (const float*)d_in[0];
    const float* centres = (const float*)d_in[1];
    const float* sigmas  = (const float*)d_in[2];
    const float* W2      = (const float*)d_in[3];
    float* out = (float*)d_out;
    short* ws  = (short*)d_ws;                  // needs 229376 B
    prep<<<dim3(56), dim3(256), 0, stream>>>(centres, sigmas, W2, ws);
    rbf_main<<<dim3(256), dim3(THREADS), 0, stream>>>(x, ws, out);
}

// Round 21
// 160.984 us; speedup vs baseline: 1.2330x; 1.2330x over previous
//
#include <hip/hip_runtime.h>

#define THREADS 512
#define DIN 60
#define HN 256
#define DOUT 360

typedef __attribute__((ext_vector_type(8))) short short8;
typedef __attribute__((ext_vector_type(16))) float f32x16;
typedef __attribute__((ext_vector_type(4))) float f32x4;
typedef __attribute__((ext_vector_type(4))) unsigned int u32x4;

// d_ws layout (bytes); total 229376 B
#define WS_CBF   0            // 2048 * 16 B = 32768  (ns-scaled centres + fold, [row][p], p=c^(row&7))
#define WS_W2    32768        // [row 0..383][pc 0..31] short8, pc=c^(row&31) = 196608 B

__device__ __forceinline__ short bf16_bits(float f) {   // prep-side only
    union { float f; unsigned u; } v; v.f = f;
    unsigned r = (v.u + 0x7FFFu + ((v.u >> 16) & 1u)) >> 16;
    return (short)(unsigned short)r;
}

__device__ __forceinline__ unsigned pk_bf16(float a, float b) {
    unsigned r;
    asm("v_cvt_pk_bf16_f32 %0, %1, %2" : "=v"(r) : "v"(a), "v"(b));
    return r;   // low16 = bf16(a), high16 = bf16(b)
}

__device__ __forceinline__ void gload16(const void* g, void* lds) {
    __builtin_amdgcn_global_load_lds(
        (const __attribute__((address_space(1))) unsigned int*)(uintptr_t)g,
        (__attribute__((address_space(3))) unsigned int*)(unsigned int)(uintptr_t)lds,
        16, 0, 0);
}

// ---------------- prep: convert/permute constants into ws (r16 verbatim) ----------------
__global__ void prep(const float* __restrict__ centres, const float* __restrict__ sigmas,
                     const float* __restrict__ W2, short* __restrict__ ws)
{
    int t = blockIdx.x * 256 + threadIdx.x;
    if (t < 12288) {
        int row = t >> 5, pc = t & 31;
        int c = pc ^ (row & 31);
        short8 v = {0,0,0,0,0,0,0,0};
        if (row < DOUT) {
            int rr = row / 12, jj = row % 12;
            int fcl = rr / 3, kk = rr % 3;
            int o = fcl * 36 + jj * 3 + kk;            // fold output col permutation
            const float* src = W2 + o * HN + c * 8;
            #pragma unroll
            for (int i = 0; i < 8; ++i) v[i] = bf16_bits(src[i]);
        }
        *(short8*)(ws + (WS_W2 / 2) + t * 8) = v;
    } else if (t < 14336) {
        // cbf (ns-fold): k<60: nsq*c_k ; k=60,61: hi/lo of -0.5*nsq*c2 (B=1,1) ;
        //                k=62,63: -0.5*nsq (B=x2hi,x2lo)
        int j = t - 12288;
        int row = j >> 3, p = j & 7;
        int c = p ^ (row & 7);
        const float* cr = centres + row * DIN;
        float sg = sigmas[row];
        union { unsigned u; float f; } nq;
        nq.u = ((unsigned)(unsigned short)bf16_bits(2.f * sg * sg * 1.44269504088896340736f)) << 16;
        const float nsq = nq.f;                        // bf16-exact
        short8 v = {0,0,0,0,0,0,0,0};
        if (c < 7) {
            #pragma unroll
            for (int i = 0; i < 8; ++i) {
                int k = c * 8 + i;
                if (k < DIN) v[i] = bf16_bits(nsq * cr[k]);
            }
        } else {   // k = 56..63
            #pragma unroll
            for (int i = 0; i < 4; ++i) v[i] = bf16_bits(nsq * cr[56 + i]);
            float c2 = 0.f;
            #pragma unroll
            for (int d = 0; d < DIN; ++d) c2 = fmaf(cr[d], cr[d], c2);
            float T = -0.5f * nsq * c2;
            union { unsigned u; float f; } th;
            th.u = ((unsigned)(unsigned short)bf16_bits(T)) << 16;   // T_hi (bf16-exact)
            v[4] = bf16_bits(th.f);
            v[5] = bf16_bits(T - th.f);
            v[6] = bf16_bits(-0.5f * nsq);
            v[7] = v[6];
        }
        *(short8*)(ws + (WS_CBF / 2) + j * 8) = v;
    }
}

// ---- one 32-row x tile -> fold-packed bf16 B-fragments (r12-verified layout) ----
__device__ __forceinline__ void load_xtile(const float* __restrict__ x, int row0,
                                           int l31, int hi, short8 xb[4]) {
    const float* xr = x + (size_t)(row0 + l31) * DIN;
    f32x4 xa[4][2];
    #pragma unroll
    for (int kt = 0; kt < 4; ++kt) {
        int k0 = kt * 16 + hi * 8;
        xa[kt][0] = *(const f32x4*)(xr + k0);
        xa[kt][1] = (k0 + 4 < DIN) ? *(const f32x4*)(xr + k0 + 4) : (f32x4){0.f,0.f,0.f,0.f};
    }
    float p2 = 0.f;
    #pragma unroll
    for (int kt = 0; kt < 4; ++kt)
        #pragma unroll
        for (int h = 0; h < 2; ++h)
            #pragma unroll
            for (int i = 0; i < 4; ++i) p2 = fmaf(xa[kt][h][i], xa[kt][h][i], p2);
    float x2v = p2 + __shfl_xor(p2, 32);
    union { unsigned u; float f; } hb; hb.u = pk_bf16(x2v, 0.f) << 16;  // x2hi (bf16-exact)
    float x2lo = x2v - hb.f;
    #pragma unroll
    for (int kt = 0; kt < 4; ++kt) {
        union { u32x4 u; short8 s; } a;
        a.u[0] = pk_bf16(xa[kt][0][0], xa[kt][0][1]);
        a.u[1] = pk_bf16(xa[kt][0][2], xa[kt][0][3]);
        a.u[2] = pk_bf16(xa[kt][1][0], xa[kt][1][1]);
        a.u[3] = pk_bf16(xa[kt][1][2], xa[kt][1][3]);
        if (kt == 3) {   // hi lanes: k=60..63 -> B = {1, 1, x2hi, x2lo}
            a.u[2] = hi ? 0x3F803F80u : a.u[2];
            a.u[3] = hi ? pk_bf16(hb.f, x2lo) : a.u[3];
        }
        xb[kt] = a.s;
    }
}

// --- main: r18 champion structure (63.0 us) + nontemporal output stores ---
__global__ __attribute__((amdgpu_flat_work_group_size(THREADS, THREADS),
                          amdgpu_waves_per_eu(2, 2)))
void rbf_main(const float* __restrict__ x, const short* __restrict__ ws,
              float* __restrict__ out)
{
    __shared__ short8 w2h[6144];     // 96 KB: 192 rows x 32 chunks (this col-half)
    __shared__ short8 cbf[2048];     // 32 KB: ns-scaled centres + fold

    const int tid  = threadIdx.x;
    const int w    = tid >> 6;
    const int lane = tid & 63;
    const int l31  = lane & 31;
    const int hi   = lane >> 5;
    const int bid  = blockIdx.x;
    // XCD pair-swizzle (r12): bid and bid^8 share rows, differ in col-half
    const int f     = (bid >> 3) & 1;
    const int sbase = (bid & 7) | ((bid >> 4) << 3);   // 0..127, bijective

    // ---- stage everything once (async DMA), one barrier total ----
    #pragma unroll
    for (int i = 0; i < 12; ++i)
        gload16(ws + (WS_W2 / 2) + ((size_t)f * 6144 + i * THREADS + tid) * 8,
                (char*)w2h + (i * THREADS + tid) * 16);
    #pragma unroll
    for (int i = 0; i < 4; ++i)
        gload16(ws + (WS_CBF / 2) + (i * THREADS + tid) * 8, (char*)cbf + (i * THREADS + tid) * 16);

    // ---- iter-0 x before the barrier (hides x latency under staging drain) ----
    short8 xb[4];
    load_xtile(x, sbase * 1024 + w * 32, l31, hi, xb);

    __syncthreads();   // LDS resident; no barriers, no LDS writes after this

    for (int it = 0; it < 4; ++it) {
        const int rb = sbase * 1024 + it * 256 + w * 32;

        f32x16 acc2[6];
        #pragma unroll
        for (int nt = 0; nt < 6; ++nt) acc2[nt] = (f32x16){};

        // ---- fused h-sweep: 8 chunks of 32 h ----
        #pragma unroll
        for (int nt1 = 0; nt1 < 8; ++nt1) {
            f32x16 a1 = (f32x16){};
            const int row = nt1 * 32 + l31;
            __builtin_amdgcn_s_setprio(1);
            #pragma unroll
            for (int kt = 0; kt < 4; ++kt) {
                short8 cf = cbf[row * 8 + ((kt * 2 + hi) ^ (row & 7))];
                a1 = __builtin_amdgcn_mfma_f32_32x32x16_bf16(cf, xb[kt], a1, 0, 0, 0);
            }
            __builtin_amdgcn_s_setprio(0);

            unsigned pwl[4][2];
            #pragma unroll
            for (int q = 0; q < 4; ++q) {
                float ph[4];
                #pragma unroll
                for (int j = 0; j < 4; ++j)
                    ph[j] = exp2f(fminf(a1[4 * q + j], 0.f));
                pwl[q][0] = pk_bf16(ph[0], ph[1]);
                pwl[q][1] = pk_bf16(ph[2], ph[3]);
            }

            #pragma unroll
            for (int m = 0; m < 2; ++m) {
                unsigned d0 = pwl[2 * m][0], s0 = pwl[2 * m + 1][0];
                unsigned d1 = pwl[2 * m][1], s1 = pwl[2 * m + 1][1];
                asm("v_permlane32_swap_b32 %0, %1" : "+v"(d0), "+v"(s0));
                asm("v_permlane32_swap_b32 %0, %1" : "+v"(d1), "+v"(s1));
                union { u32x4 u; short8 s; } bfr;
                bfr.u[0] = d0; bfr.u[1] = d1; bfr.u[2] = s0; bfr.u[3] = s1;
                const int ktg = nt1 * 2 + m;

                __builtin_amdgcn_s_setprio(1);
                #pragma unroll
                for (int nt = 0; nt < 6; ++nt) {
                    int lrow = nt * 32 + l31;
                    short8 wf = w2h[lrow * 32 + ((ktg * 2 + hi) ^ l31)];
                    acc2[nt] = __builtin_amdgcn_mfma_f32_32x32x16_bf16(wf, bfr.s, acc2[nt], 0, 0, 0);
                }
                __builtin_amdgcn_s_setprio(0);
            }
        }

        // ---- next iter's x (issued before stores; latency hides under store burst) ----
        if (it < 3)
            load_xtile(x, rb + 256, l31, hi, xb);

        // ---- stores: nontemporal (write-once data; keeps L2 for W2/x reads) ----
        {
            float* op = out + (size_t)(rb + l31) * DOUT;
            #pragma unroll
            for (int nt = 0; nt < 6; ++nt) {
                #pragma unroll
                for (int q = 0; q < 4; ++q) {
                    int col = f * 192 + nt * 32 + q * 8 + hi * 4;
                    if (col < DOUT) {
                        f32x4 v;
                        v[0] = acc2[nt][4 * q + 0]; v[1] = acc2[nt][4 * q + 1];
                        v[2] = acc2[nt][4 * q + 2]; v[3] = acc2[nt][4 * q + 3];
                        __builtin_nontemporal_store(v, (f32x4*)(op + col));
                    }
                }
            }
        }
    }
}

extern "C" void kernel_launch(void* const* d_in, const int* in_sizes, int n_in,
                              void* d_out, int out_size, void* d_ws, size_t ws_size,
                              hipStream_t stream) {
    const float* x       = (const float*)d_in[0];
    const float* centres = (const float*)d_in[1];
    const float* sigmas  = (const float*)d_in[2];
    const float* W2      = (const float*)d_in[3];
    float* out = (float*)d_out;
    short* ws  = (short*)d_ws;                  // needs 229376 B
    prep<<<dim3(56), dim3(256), 0, stream>>>(centres, sigmas, W2, ws);
    rbf_main<<<dim3(256), dim3(THREADS), 0, stream>>>(x, ws, out);
}

// Round 22
// 62.736 us; speedup vs baseline: 3.1640x; 2.5660x over previous
//
#include <hip/hip_runtime.h>

#define THREADS 512
#define DIN 60
#define HN 256
#define DOUT 360

typedef __attribute__((ext_vector_type(8))) short short8;
typedef __attribute__((ext_vector_type(16))) float f32x16;
typedef __attribute__((ext_vector_type(4))) float f32x4;
typedef __attribute__((ext_vector_type(4))) unsigned int u32x4;

// d_ws layout (bytes); total 229376 B
#define WS_CBF   0            // 2048 * 16 B = 32768  (ns-scaled centres + fold, [row][p], p=c^(row&7))
#define WS_W2    32768        // [row 0..383][pc 0..31] short8, pc=c^(row&31) = 196608 B

__device__ __forceinline__ short bf16_bits(float f) {   // prep-side only
    union { float f; unsigned u; } v; v.f = f;
    unsigned r = (v.u + 0x7FFFu + ((v.u >> 16) & 1u)) >> 16;
    return (short)(unsigned short)r;
}

__device__ __forceinline__ unsigned pk_bf16(float a, float b) {
    unsigned r;
    asm("v_cvt_pk_bf16_f32 %0, %1, %2" : "=v"(r) : "v"(a), "v"(b));
    return r;   // low16 = bf16(a), high16 = bf16(b)
}

__device__ __forceinline__ void gload16(const void* g, void* lds) {
    __builtin_amdgcn_global_load_lds(
        (const __attribute__((address_space(1))) unsigned int*)(uintptr_t)g,
        (__attribute__((address_space(3))) unsigned int*)(unsigned int)(uintptr_t)lds,
        16, 0, 0);
}

// ---------------- prep: convert/permute constants into ws (r16 verbatim) ----------------
__global__ void prep(const float* __restrict__ centres, const float* __restrict__ sigmas,
                     const float* __restrict__ W2, short* __restrict__ ws)
{
    int t = blockIdx.x * 256 + threadIdx.x;
    if (t < 12288) {
        int row = t >> 5, pc = t & 31;
        int c = pc ^ (row & 31);
        short8 v = {0,0,0,0,0,0,0,0};
        if (row < DOUT) {
            int rr = row / 12, jj = row % 12;
            int fcl = rr / 3, kk = rr % 3;
            int o = fcl * 36 + jj * 3 + kk;            // fold output col permutation
            const float* src = W2 + o * HN + c * 8;
            #pragma unroll
            for (int i = 0; i < 8; ++i) v[i] = bf16_bits(src[i]);
        }
        *(short8*)(ws + (WS_W2 / 2) + t * 8) = v;
    } else if (t < 14336) {
        // cbf (ns-fold): k<60: nsq*c_k ; k=60,61: hi/lo of -0.5*nsq*c2 (B=1,1) ;
        //                k=62,63: -0.5*nsq (B=x2hi,x2lo)
        int j = t - 12288;
        int row = j >> 3, p = j & 7;
        int c = p ^ (row & 7);
        const float* cr = centres + row * DIN;
        float sg = sigmas[row];
        union { unsigned u; float f; } nq;
        nq.u = ((unsigned)(unsigned short)bf16_bits(2.f * sg * sg * 1.44269504088896340736f)) << 16;
        const float nsq = nq.f;                        // bf16-exact
        short8 v = {0,0,0,0,0,0,0,0};
        if (c < 7) {
            #pragma unroll
            for (int i = 0; i < 8; ++i) {
                int k = c * 8 + i;
                if (k < DIN) v[i] = bf16_bits(nsq * cr[k]);
            }
        } else {   // k = 56..63
            #pragma unroll
            for (int i = 0; i < 4; ++i) v[i] = bf16_bits(nsq * cr[56 + i]);
            float c2 = 0.f;
            #pragma unroll
            for (int d = 0; d < DIN; ++d) c2 = fmaf(cr[d], cr[d], c2);
            float T = -0.5f * nsq * c2;
            union { unsigned u; float f; } th;
            th.u = ((unsigned)(unsigned short)bf16_bits(T)) << 16;   // T_hi (bf16-exact)
            v[4] = bf16_bits(th.f);
            v[5] = bf16_bits(T - th.f);
            v[6] = bf16_bits(-0.5f * nsq);
            v[7] = v[6];
        }
        *(short8*)(ws + (WS_CBF / 2) + j * 8) = v;
    }
}

// ---- one 32-row x tile -> fold-packed bf16 B-fragments (r12-verified layout) ----
__device__ __forceinline__ void load_xtile(const float* __restrict__ x, int row0,
                                           int l31, int hi, short8 xb[4]) {
    const float* xr = x + (size_t)(row0 + l31) * DIN;
    f32x4 xa[4][2];
    #pragma unroll
    for (int kt = 0; kt < 4; ++kt) {
        int k0 = kt * 16 + hi * 8;
        xa[kt][0] = *(const f32x4*)(xr + k0);
        xa[kt][1] = (k0 + 4 < DIN) ? *(const f32x4*)(xr + k0 + 4) : (f32x4){0.f,0.f,0.f,0.f};
    }
    float p2 = 0.f;
    #pragma unroll
    for (int kt = 0; kt < 4; ++kt)
        #pragma unroll
        for (int h = 0; h < 2; ++h)
            #pragma unroll
            for (int i = 0; i < 4; ++i) p2 = fmaf(xa[kt][h][i], xa[kt][h][i], p2);
    float x2v = p2 + __shfl_xor(p2, 32);
    union { unsigned u; float f; } hb; hb.u = pk_bf16(x2v, 0.f) << 16;  // x2hi (bf16-exact)
    float x2lo = x2v - hb.f;
    #pragma unroll
    for (int kt = 0; kt < 4; ++kt) {
        union { u32x4 u; short8 s; } a;
        a.u[0] = pk_bf16(xa[kt][0][0], xa[kt][0][1]);
        a.u[1] = pk_bf16(xa[kt][0][2], xa[kt][0][3]);
        a.u[2] = pk_bf16(xa[kt][1][0], xa[kt][1][1]);
        a.u[3] = pk_bf16(xa[kt][1][2], xa[kt][1][3]);
        if (kt == 3) {   // hi lanes: k=60..63 -> B = {1, 1, x2hi, x2lo}
            a.u[2] = hi ? 0x3F803F80u : a.u[2];
            a.u[3] = hi ? pk_bf16(hb.f, x2lo) : a.u[3];
        }
        xb[kt] = a.s;
    }
}

// --- main: r18 champion structure (63.0 us), regular coalesced stores ---
__global__ __attribute__((amdgpu_flat_work_group_size(THREADS, THREADS),
                          amdgpu_waves_per_eu(2, 2)))
void rbf_main(const float* __restrict__ x, const short* __restrict__ ws,
              float* __restrict__ out)
{
    __shared__ short8 w2h[6144];     // 96 KB: 192 rows x 32 chunks (this col-half)
    __shared__ short8 cbf[2048];     // 32 KB: ns-scaled centres + fold

    const int tid  = threadIdx.x;
    const int w    = tid >> 6;
    const int lane = tid & 63;
    const int l31  = lane & 31;
    const int hi   = lane >> 5;
    const int bid  = blockIdx.x;
    // XCD pair-swizzle (r12): bid and bid^8 share rows, differ in col-half
    const int f     = (bid >> 3) & 1;
    const int sbase = (bid & 7) | ((bid >> 4) << 3);   // 0..127, bijective

    // ---- stage everything once (async DMA), one barrier total ----
    #pragma unroll
    for (int i = 0; i < 12; ++i)
        gload16(ws + (WS_W2 / 2) + ((size_t)f * 6144 + i * THREADS + tid) * 8,
                (char*)w2h + (i * THREADS + tid) * 16);
    #pragma unroll
    for (int i = 0; i < 4; ++i)
        gload16(ws + (WS_CBF / 2) + (i * THREADS + tid) * 8, (char*)cbf + (i * THREADS + tid) * 16);

    // ---- iter-0 x before the barrier (hides x latency under staging drain) ----
    short8 xb[4];
    load_xtile(x, sbase * 1024 + w * 32, l31, hi, xb);

    __syncthreads();   // LDS resident; no barriers, no LDS writes after this

    for (int it = 0; it < 4; ++it) {
        const int rb = sbase * 1024 + it * 256 + w * 32;

        f32x16 acc2[6];
        #pragma unroll
        for (int nt = 0; nt < 6; ++nt) acc2[nt] = (f32x16){};

        // ---- fused h-sweep: 8 chunks of 32 h ----
        #pragma unroll
        for (int nt1 = 0; nt1 < 8; ++nt1) {
            f32x16 a1 = (f32x16){};
            const int row = nt1 * 32 + l31;
            __builtin_amdgcn_s_setprio(1);
            #pragma unroll
            for (int kt = 0; kt < 4; ++kt) {
                short8 cf = cbf[row * 8 + ((kt * 2 + hi) ^ (row & 7))];
                a1 = __builtin_amdgcn_mfma_f32_32x32x16_bf16(cf, xb[kt], a1, 0, 0, 0);
            }
            __builtin_amdgcn_s_setprio(0);

            unsigned pwl[4][2];
            #pragma unroll
            for (int q = 0; q < 4; ++q) {
                float ph[4];
                #pragma unroll
                for (int j = 0; j < 4; ++j)
                    ph[j] = exp2f(fminf(a1[4 * q + j], 0.f));
                pwl[q][0] = pk_bf16(ph[0], ph[1]);
                pwl[q][1] = pk_bf16(ph[2], ph[3]);
            }

            #pragma unroll
            for (int m = 0; m < 2; ++m) {
                unsigned d0 = pwl[2 * m][0], s0 = pwl[2 * m + 1][0];
                unsigned d1 = pwl[2 * m][1], s1 = pwl[2 * m + 1][1];
                asm("v_permlane32_swap_b32 %0, %1" : "+v"(d0), "+v"(s0));
                asm("v_permlane32_swap_b32 %0, %1" : "+v"(d1), "+v"(s1));
                union { u32x4 u; short8 s; } bfr;
                bfr.u[0] = d0; bfr.u[1] = d1; bfr.u[2] = s0; bfr.u[3] = s1;
                const int ktg = nt1 * 2 + m;

                __builtin_amdgcn_s_setprio(1);
                #pragma unroll
                for (int nt = 0; nt < 6; ++nt) {
                    int lrow = nt * 32 + l31;
                    short8 wf = w2h[lrow * 32 + ((ktg * 2 + hi) ^ l31)];
                    acc2[nt] = __builtin_amdgcn_mfma_f32_32x32x16_bf16(wf, bfr.s, acc2[nt], 0, 0, 0);
                }
                __builtin_amdgcn_s_setprio(0);
            }
        }

        // ---- next iter's x (issued before stores; latency hides under store burst) ----
        if (it < 3)
            load_xtile(x, rb + 256, l31, hi, xb);

        // ---- stores (r12-verified pattern): row rb+l31, 4 cols per reg-quad ----
        {
            float* op = out + (size_t)(rb + l31) * DOUT;
            #pragma unroll
            for (int nt = 0; nt < 6; ++nt) {
                #pragma unroll
                for (int q = 0; q < 4; ++q) {
                    int col = f * 192 + nt * 32 + q * 8 + hi * 4;
                    if (col < DOUT) {
                        f32x4 v;
                        v[0] = acc2[nt][4 * q + 0]; v[1] = acc2[nt][4 * q + 1];
                        v[2] = acc2[nt][4 * q + 2]; v[3] = acc2[nt][4 * q + 3];
                        *(f32x4*)(op + col) = v;
                    }
                }
            }
        }
    }
}

extern "C" void kernel_launch(void* const* d_in, const int* in_sizes, int n_in,
                              void* d_out, int out_size, void* d_ws, size_t ws_size,
                              hipStream_t stream) {
    const float* x       = (const float*)d_in[0];
    const float* centres = (const float*)d_in[1];
    const float* sigmas  = (const float*)d_in[2];
    const float* W2      = (const float*)d_in[3];
    float* out = (float*)d_out;
    short* ws  = (short*)d_ws;                  // needs 229376 B
    prep<<<dim3(56), dim3(256), 0, stream>>>(centres, sigmas, W2, ws);
    rbf_main<<<dim3(256), dim3(THREADS), 0, stream>>>(x, ws, out);
}